// Round 1
// baseline (639.585 us; speedup 1.0000x reference)
//
#include <hip/hip_runtime.h>
#include <hip/hip_bf16.h>
#include <cstddef>

#define NN 50000
#define EE 800000
#define TE 850000   // EE + NN self loops
#define INC 256
#define C1 128      // heads(2) * hid(64)
#define C2 64
#define NCHUNK 49   // ceil(NN/1024)

// ---------------- CSR build ----------------

__global__ void k_zero(int* p, int n) {
    int i = blockIdx.x * blockDim.x + threadIdx.x;
    if (i < n) p[i] = 0;
}

__global__ void k_count(const int* __restrict__ ei, int* __restrict__ deg) {
    int e = blockIdx.x * blockDim.x + threadIdx.x;
    if (e >= TE) return;
    int dst = (e < EE) ? ei[EE + e] : (e - EE);
    atomicAdd(&deg[dst], 1);
}

// chunked inclusive scan, chunk = 1024
__global__ void k_scan1(const int* __restrict__ deg, int* __restrict__ incl,
                        int* __restrict__ totals) {
    __shared__ int lds[1024];
    int t = threadIdx.x;
    int i = blockIdx.x * 1024 + t;
    int v = (i < NN) ? deg[i] : 0;
    lds[t] = v;
    __syncthreads();
    for (int off = 1; off < 1024; off <<= 1) {
        int add = (t >= off) ? lds[t - off] : 0;
        __syncthreads();
        lds[t] += add;
        __syncthreads();
    }
    if (i < NN) incl[i] = lds[t];
    if (t == 1023) totals[blockIdx.x] = lds[t];
}

__global__ void k_scan2(const int* __restrict__ totals, int* __restrict__ chunkoff) {
    int t = threadIdx.x;  // one wave of 64, NCHUNK=49 <= 64
    int orig = (t < NCHUNK) ? totals[t] : 0;
    int v = orig;
    for (int off = 1; off < 64; off <<= 1) {
        int u = __shfl_up(v, off, 64);
        if (t >= off) v += u;
    }
    if (t < NCHUNK) chunkoff[t] = v - orig;  // exclusive
}

__global__ void k_scan3(const int* __restrict__ incl, const int* __restrict__ deg,
                        const int* __restrict__ chunkoff, int* __restrict__ rowstart,
                        int* __restrict__ writeptr) {
    int i = blockIdx.x * blockDim.x + threadIdx.x;
    if (i == 0) rowstart[NN] = TE;
    if (i >= NN) return;
    int rs = incl[i] - deg[i] + chunkoff[i >> 10];
    rowstart[i] = rs;
    writeptr[i] = rs;
}

__global__ void k_scatter(const int* __restrict__ ei, int* __restrict__ writeptr,
                          int* __restrict__ ssrc) {
    int e = blockIdx.x * blockDim.x + threadIdx.x;
    if (e >= TE) return;
    int s, d;
    if (e < EE) { s = ei[e]; d = ei[EE + e]; }
    else        { s = e - EE; d = s; }
    int pos = atomicAdd(&writeptr[d], 1);
    ssrc[pos] = s;
}

// ---------------- fp32 tiled GEMM: C[M,NCOL] = A[M,K] @ W[K,NCOL] + bias ----------------
// 64x64 tile, BK=16, 256 threads, 4x4 micro-tile.

template <int K, int NCOL>
__global__ __launch_bounds__(256) void k_gemm(const float* __restrict__ A,
                                              const float* __restrict__ W,
                                              const float* __restrict__ bias,
                                              float* __restrict__ C, int M) {
    __shared__ float As[16][65];  // As[k][m]
    __shared__ float Bs[16][65];  // Bs[k][n]
    int tid = threadIdx.x;
    int bm = blockIdx.x * 64;
    int bn = blockIdx.y * 64;
    int tm = (tid >> 4) * 4;
    int tn = (tid & 15) * 4;
    int ar = tid >> 2;         // 0..63
    int ak = (tid & 3) * 4;    // 0,4,8,12
    int bk = tid >> 4;         // 0..15
    int bn4 = (tid & 15) * 4;  // 0..60

    float acc[4][4] = {};
    for (int k0 = 0; k0 < K; k0 += 16) {
        float4 av = make_float4(0.f, 0.f, 0.f, 0.f);
        if (bm + ar < M)
            av = *(const float4*)&A[(size_t)(bm + ar) * K + k0 + ak];
        As[ak + 0][ar] = av.x; As[ak + 1][ar] = av.y;
        As[ak + 2][ar] = av.z; As[ak + 3][ar] = av.w;
        float4 bv = *(const float4*)&W[(size_t)(k0 + bk) * NCOL + bn + bn4];
        Bs[bk][bn4 + 0] = bv.x; Bs[bk][bn4 + 1] = bv.y;
        Bs[bk][bn4 + 2] = bv.z; Bs[bk][bn4 + 3] = bv.w;
        __syncthreads();
#pragma unroll
        for (int k = 0; k < 16; k++) {
            float a0 = As[k][tm + 0], a1 = As[k][tm + 1];
            float a2 = As[k][tm + 2], a3 = As[k][tm + 3];
            float b0 = Bs[k][tn + 0], b1 = Bs[k][tn + 1];
            float b2 = Bs[k][tn + 2], b3 = Bs[k][tn + 3];
            acc[0][0] += a0 * b0; acc[0][1] += a0 * b1; acc[0][2] += a0 * b2; acc[0][3] += a0 * b3;
            acc[1][0] += a1 * b0; acc[1][1] += a1 * b1; acc[1][2] += a1 * b2; acc[1][3] += a1 * b3;
            acc[2][0] += a2 * b0; acc[2][1] += a2 * b1; acc[2][2] += a2 * b2; acc[2][3] += a2 * b3;
            acc[3][0] += a3 * b0; acc[3][1] += a3 * b1; acc[3][2] += a3 * b2; acc[3][3] += a3 * b3;
        }
        __syncthreads();
    }
    float4 bb = *(const float4*)&bias[bn + tn];
#pragma unroll
    for (int mi = 0; mi < 4; mi++) {
        int row = bm + tm + mi;
        if (row >= M) continue;
        float4 o = make_float4(acc[mi][0] + bb.x, acc[mi][1] + bb.y,
                               acc[mi][2] + bb.z, acc[mi][3] + bb.w);
        *(float4*)&C[(size_t)row * NCOL + bn + tn] = o;
    }
}

// ---------------- fused per-node GATv2 aggregation ----------------
// Layer 1: block=128 (2 waves), wave = head, lane = channel.

__global__ __launch_bounds__(128) void k_node1(
    const float* __restrict__ xl, const float* __restrict__ xr,
    const int* __restrict__ rowstart, const int* __restrict__ ssrc,
    const float* __restrict__ att, const float* __restrict__ bias,
    const float* __restrict__ g, const float* __restrict__ b,
    const float* __restrict__ m, const float* __restrict__ v,
    float* __restrict__ out) {
    int i = blockIdx.x;
    int t = threadIdx.x;  // 0..127, head = t>>6, c = t&63
    float xr_t = xr[(size_t)i * C1 + t];
    float att_t = att[t];  // att1 flat (2,64)=128
    int row = rowstart[i], end = rowstart[i + 1];
    float s = 0.f, acc = 0.f;
    for (int j = row; j < end; j++) {
        int src = ssrc[j];
        float vv = xl[(size_t)src * C1 + t];
        float e = vv + xr_t;
        e = (e > 0.f) ? e : 0.2f * e;
        float w = att_t * e;
#pragma unroll
        for (int o = 32; o >= 1; o >>= 1) w += __shfl_xor(w, o, 64);
        float p = __expf(w);
        s += p;
        acc += p * vv;
    }
    float o = acc / s + bias[t];
    o = (o - m[t]) * rsqrtf(v[t] + 1e-5f) * g[t] + b[t];
    o = (o > 0.f) ? o : (__expf(o) - 1.f);  // ELU
    out[(size_t)i * C1 + t] = o;
}

// Layer 2 (H=1,C=64) + classifier fused: block = 1 wave per node.
__global__ __launch_bounds__(64) void k_node2(
    const float* __restrict__ xl, const float* __restrict__ xr,
    const int* __restrict__ rowstart, const int* __restrict__ ssrc,
    const float* __restrict__ att, const float* __restrict__ bias,
    const float* __restrict__ g, const float* __restrict__ b,
    const float* __restrict__ m, const float* __restrict__ v,
    const float* __restrict__ Wc, const float* __restrict__ bc,
    float* __restrict__ out) {
    int i = blockIdx.x;
    int t = threadIdx.x;  // 0..63
    float xr_t = xr[(size_t)i * C2 + t];
    float att_t = att[t];
    int row = rowstart[i], end = rowstart[i + 1];
    float s = 0.f, acc = 0.f;
    for (int j = row; j < end; j++) {
        int src = ssrc[j];
        float vv = xl[(size_t)src * C2 + t];
        float e = vv + xr_t;
        e = (e > 0.f) ? e : 0.2f * e;
        float w = att_t * e;
#pragma unroll
        for (int o = 32; o >= 1; o >>= 1) w += __shfl_xor(w, o, 64);
        float p = __expf(w);
        s += p;
        acc += p * vv;
    }
    float o = acc / s + bias[t];
    o = (o - m[t]) * rsqrtf(v[t] + 1e-5f) * g[t] + b[t];
    o = (o > 0.f) ? o : (__expf(o) - 1.f);  // ELU
    // classifier: sigmoid(h2 . Wc + bc)
    float z = o * Wc[t];
#pragma unroll
    for (int off = 32; off >= 1; off >>= 1) z += __shfl_xor(z, off, 64);
    if (t == 0) out[i] = 1.f / (1.f + __expf(-(z + bc[0])));
}

// ---------------- launch ----------------

extern "C" void kernel_launch(void* const* d_in, const int* in_sizes, int n_in,
                              void* d_out, int out_size, void* d_ws, size_t ws_size,
                              hipStream_t stream) {
    const float* x    = (const float*)d_in[0];
    const int*   ei   = (const int*)d_in[1];
    const float* W1l  = (const float*)d_in[2];
    const float* b1l  = (const float*)d_in[3];
    const float* W1r  = (const float*)d_in[4];
    const float* b1r  = (const float*)d_in[5];
    const float* att1 = (const float*)d_in[6];
    const float* bias1= (const float*)d_in[7];
    const float* bn1g = (const float*)d_in[8];
    const float* bn1b = (const float*)d_in[9];
    const float* bn1m = (const float*)d_in[10];
    const float* bn1v = (const float*)d_in[11];
    const float* W2l  = (const float*)d_in[12];
    const float* b2l  = (const float*)d_in[13];
    const float* W2r  = (const float*)d_in[14];
    const float* b2r  = (const float*)d_in[15];
    const float* att2 = (const float*)d_in[16];
    const float* bias2= (const float*)d_in[17];
    const float* bn2g = (const float*)d_in[18];
    const float* bn2b = (const float*)d_in[19];
    const float* bn2m = (const float*)d_in[20];
    const float* bn2v = (const float*)d_in[21];
    const float* Wc   = (const float*)d_in[22];
    const float* bc   = (const float*)d_in[23];
    float* out = (float*)d_out;

    // workspace layout (256B-aligned slots)
    char* ws = (char*)d_ws;
    size_t off = 0;
    auto alloc = [&](size_t bytes) {
        size_t o = off;
        off += (bytes + 255) & ~(size_t)255;
        return o;
    };
    float* xl1 = (float*)(ws + alloc((size_t)NN * C1 * 4));  // reused as xl2
    float* xr1 = (float*)(ws + alloc((size_t)NN * C1 * 4));  // reused as xr2
    float* h1  = (float*)(ws + alloc((size_t)NN * C1 * 4));
    int* deg      = (int*)(ws + alloc((size_t)NN * 4));
    int* incl     = (int*)(ws + alloc((size_t)NN * 4));
    int* rowstart = (int*)(ws + alloc((size_t)(NN + 1) * 4));
    int* writeptr = (int*)(ws + alloc((size_t)NN * 4));
    int* totals   = (int*)(ws + alloc(64 * 4));
    int* chunkoff = (int*)(ws + alloc(64 * 4));
    int* ssrc     = (int*)(ws + alloc((size_t)TE * 4));
    float* xl2 = xl1;
    float* xr2 = xr1;

    // CSR build
    k_zero<<<(NN + 255) / 256, 256, 0, stream>>>(deg, NN);
    k_count<<<(TE + 255) / 256, 256, 0, stream>>>(ei, deg);
    k_scan1<<<NCHUNK, 1024, 0, stream>>>(deg, incl, totals);
    k_scan2<<<1, 64, 0, stream>>>(totals, chunkoff);
    k_scan3<<<(NN + 255) / 256, 256, 0, stream>>>(incl, deg, chunkoff, rowstart, writeptr);
    k_scatter<<<(TE + 255) / 256, 256, 0, stream>>>(ei, writeptr, ssrc);

    // layer 1
    dim3 g1((NN + 63) / 64, C1 / 64);
    k_gemm<INC, C1><<<g1, 256, 0, stream>>>(x, W1l, b1l, xl1, NN);
    k_gemm<INC, C1><<<g1, 256, 0, stream>>>(x, W1r, b1r, xr1, NN);
    k_node1<<<NN, 128, 0, stream>>>(xl1, xr1, rowstart, ssrc, att1, bias1,
                                    bn1g, bn1b, bn1m, bn1v, h1);

    // layer 2 (+classifier fused)
    dim3 g2((NN + 63) / 64, C2 / 64);
    k_gemm<C1, C2><<<g2, 256, 0, stream>>>(h1, W2l, b2l, xl2, NN);
    k_gemm<C1, C2><<<g2, 256, 0, stream>>>(h1, W2r, b2r, xr2, NN);
    k_node2<<<NN, 64, 0, stream>>>(xl2, xr2, rowstart, ssrc, att2, bias2,
                                   bn2g, bn2b, bn2m, bn2v, Wc, bc, out);
}

// Round 2
// 558.135 us; speedup vs baseline: 1.1459x; 1.1459x over previous
//
#include <hip/hip_runtime.h>
#include <hip/hip_bf16.h>
#include <cstddef>

#define NN 50000
#define EE 800000
#define TE 850000   // EE + NN self loops
#define INC 256
#define C1 128      // heads(2) * hid(64)
#define C2 64
#define NCHUNK 49   // ceil(NN/1024)

// ---------------- CSR build ----------------

__global__ void k_zero(int* p, int n) {
    int i = blockIdx.x * blockDim.x + threadIdx.x;
    if (i < n) p[i] = 0;
}

__global__ void k_count(const int* __restrict__ ei, int* __restrict__ deg) {
    int e = blockIdx.x * blockDim.x + threadIdx.x;
    if (e >= TE) return;
    int dst = (e < EE) ? ei[EE + e] : (e - EE);
    atomicAdd(&deg[dst], 1);
}

// chunked inclusive scan, chunk = 1024
__global__ void k_scan1(const int* __restrict__ deg, int* __restrict__ incl,
                        int* __restrict__ totals) {
    __shared__ int lds[1024];
    int t = threadIdx.x;
    int i = blockIdx.x * 1024 + t;
    int v = (i < NN) ? deg[i] : 0;
    lds[t] = v;
    __syncthreads();
    for (int off = 1; off < 1024; off <<= 1) {
        int add = (t >= off) ? lds[t - off] : 0;
        __syncthreads();
        lds[t] += add;
        __syncthreads();
    }
    if (i < NN) incl[i] = lds[t];
    if (t == 1023) totals[blockIdx.x] = lds[t];
}

__global__ void k_scan2(const int* __restrict__ totals, int* __restrict__ chunkoff) {
    int t = threadIdx.x;  // one wave of 64, NCHUNK=49 <= 64
    int orig = (t < NCHUNK) ? totals[t] : 0;
    int v = orig;
    for (int off = 1; off < 64; off <<= 1) {
        int u = __shfl_up(v, off, 64);
        if (t >= off) v += u;
    }
    if (t < NCHUNK) chunkoff[t] = v - orig;  // exclusive
}

__global__ void k_scan3(const int* __restrict__ incl, const int* __restrict__ deg,
                        const int* __restrict__ chunkoff, int* __restrict__ rowstart,
                        int* __restrict__ writeptr) {
    int i = blockIdx.x * blockDim.x + threadIdx.x;
    if (i == 0) rowstart[NN] = TE;
    if (i >= NN) return;
    int rs = incl[i] - deg[i] + chunkoff[i >> 10];
    rowstart[i] = rs;
    writeptr[i] = rs;
}

__global__ void k_scatter(const int* __restrict__ ei, int* __restrict__ writeptr,
                          int* __restrict__ ssrc) {
    int e = blockIdx.x * blockDim.x + threadIdx.x;
    if (e >= TE) return;
    int s, d;
    if (e < EE) { s = ei[e]; d = ei[EE + e]; }
    else        { s = e - EE; d = s; }
    int pos = atomicAdd(&writeptr[d], 1);
    ssrc[pos] = s;
}

// ---------------- fp32 tiled GEMM, fused l|r weights ----------------
// C[M, 2*HALF] = A[M,K] @ [Wl | Wr] + [bl | br]; 64x64 tile, BK=16, 256 thr, 4x4 micro.

template <int K, int HALF>
__global__ __launch_bounds__(256) void k_gemm2(const float* __restrict__ A,
                                               const float* __restrict__ Wl,
                                               const float* __restrict__ Wr,
                                               const float* __restrict__ bl,
                                               const float* __restrict__ br,
                                               float* __restrict__ C, int M) {
    __shared__ float As[16][65];  // As[k][m]
    __shared__ float Bs[16][65];  // Bs[k][n]
    const int NCOL = 2 * HALF;
    int tid = threadIdx.x;
    int bm = blockIdx.x * 64;
    int bn = blockIdx.y * 64;   // tile fully inside one half (HALF % 64 == 0)
    const float* W = (bn < HALF) ? Wl : Wr;
    const float* bb_ptr = (bn < HALF) ? bl : br;
    int bcol = (bn < HALF) ? bn : bn - HALF;  // column base within W (stride HALF)

    int tm = (tid >> 4) * 4;
    int tn = (tid & 15) * 4;
    int ar = tid >> 2;         // 0..63
    int ak = (tid & 3) * 4;    // 0,4,8,12
    int bk = tid >> 4;         // 0..15
    int bn4 = (tid & 15) * 4;  // 0..60

    float acc[4][4] = {};
    for (int k0 = 0; k0 < K; k0 += 16) {
        float4 av = make_float4(0.f, 0.f, 0.f, 0.f);
        if (bm + ar < M)
            av = *(const float4*)&A[(size_t)(bm + ar) * K + k0 + ak];
        As[ak + 0][ar] = av.x; As[ak + 1][ar] = av.y;
        As[ak + 2][ar] = av.z; As[ak + 3][ar] = av.w;
        float4 bv = *(const float4*)&W[(size_t)(k0 + bk) * HALF + bcol + bn4];
        Bs[bk][bn4 + 0] = bv.x; Bs[bk][bn4 + 1] = bv.y;
        Bs[bk][bn4 + 2] = bv.z; Bs[bk][bn4 + 3] = bv.w;
        __syncthreads();
#pragma unroll
        for (int k = 0; k < 16; k++) {
            float a0 = As[k][tm + 0], a1 = As[k][tm + 1];
            float a2 = As[k][tm + 2], a3 = As[k][tm + 3];
            float b0 = Bs[k][tn + 0], b1 = Bs[k][tn + 1];
            float b2 = Bs[k][tn + 2], b3 = Bs[k][tn + 3];
            acc[0][0] += a0 * b0; acc[0][1] += a0 * b1; acc[0][2] += a0 * b2; acc[0][3] += a0 * b3;
            acc[1][0] += a1 * b0; acc[1][1] += a1 * b1; acc[1][2] += a1 * b2; acc[1][3] += a1 * b3;
            acc[2][0] += a2 * b0; acc[2][1] += a2 * b1; acc[2][2] += a2 * b2; acc[2][3] += a2 * b3;
            acc[3][0] += a3 * b0; acc[3][1] += a3 * b1; acc[3][2] += a3 * b2; acc[3][3] += a3 * b3;
        }
        __syncthreads();
    }
    float4 bb = *(const float4*)&bb_ptr[bcol + tn];
#pragma unroll
    for (int mi = 0; mi < 4; mi++) {
        int row = bm + tm + mi;
        if (row >= M) continue;
        float4 o = make_float4(acc[mi][0] + bb.x, acc[mi][1] + bb.y,
                               acc[mi][2] + bb.z, acc[mi][3] + bb.w);
        *(float4*)&C[(size_t)row * NCOL + bn + tn] = o;
    }
}

// ---------------- fused per-node GATv2 aggregation ----------------
// xlr layout: row stride 2*CH; cols [0,CH) = xl, [CH,2CH) = xr.
// 4-wide edge unroll: 4 independent gather->butterfly->exp chains for ILP.

#define LRELU(e) ((e) > 0.f ? (e) : 0.2f * (e))

// Layer 1: block=128 (2 waves), wave = head, lane = channel, CH=128.
__global__ __launch_bounds__(128) void k_node1(
    const float* __restrict__ xlr,
    const int* __restrict__ rowstart, const int* __restrict__ ssrc,
    const float* __restrict__ att, const float* __restrict__ bias,
    const float* __restrict__ g, const float* __restrict__ b,
    const float* __restrict__ m, const float* __restrict__ v,
    float* __restrict__ out) {
    int i = blockIdx.x;
    int t = threadIdx.x;  // 0..127, head = t>>6, c = t&63
    float xr_t = xlr[(size_t)i * 256 + 128 + t];
    float att_t = att[t];  // att1 flat (2,64)=128
    int row = rowstart[i], end = rowstart[i + 1];
    float s = 0.f, acc = 0.f;
    int j = row;
    for (; j + 4 <= end; j += 4) {
        int s0 = ssrc[j], s1 = ssrc[j + 1], s2 = ssrc[j + 2], s3 = ssrc[j + 3];
        float v0 = xlr[(size_t)s0 * 256 + t];
        float v1 = xlr[(size_t)s1 * 256 + t];
        float v2 = xlr[(size_t)s2 * 256 + t];
        float v3 = xlr[(size_t)s3 * 256 + t];
        float w0 = att_t * LRELU(v0 + xr_t);
        float w1 = att_t * LRELU(v1 + xr_t);
        float w2 = att_t * LRELU(v2 + xr_t);
        float w3 = att_t * LRELU(v3 + xr_t);
#pragma unroll
        for (int o = 32; o >= 1; o >>= 1) {
            w0 += __shfl_xor(w0, o, 64);
            w1 += __shfl_xor(w1, o, 64);
            w2 += __shfl_xor(w2, o, 64);
            w3 += __shfl_xor(w3, o, 64);
        }
        float p0 = __expf(w0), p1 = __expf(w1), p2 = __expf(w2), p3 = __expf(w3);
        s += (p0 + p1) + (p2 + p3);
        acc += p0 * v0 + p1 * v1 + p2 * v2 + p3 * v3;
    }
    for (; j < end; j++) {
        int src = ssrc[j];
        float vv = xlr[(size_t)src * 256 + t];
        float w = att_t * LRELU(vv + xr_t);
#pragma unroll
        for (int o = 32; o >= 1; o >>= 1) w += __shfl_xor(w, o, 64);
        float p = __expf(w);
        s += p;
        acc += p * vv;
    }
    float o = acc / s + bias[t];
    o = (o - m[t]) * rsqrtf(v[t] + 1e-5f) * g[t] + b[t];
    o = (o > 0.f) ? o : (__expf(o) - 1.f);  // ELU
    out[(size_t)i * C1 + t] = o;
}

// Layer 2 (H=1,C=64) + classifier fused: 2 nodes per block (2 waves), CH=64.
__global__ __launch_bounds__(128) void k_node2(
    const float* __restrict__ xlr,
    const int* __restrict__ rowstart, const int* __restrict__ ssrc,
    const float* __restrict__ att, const float* __restrict__ bias,
    const float* __restrict__ g, const float* __restrict__ b,
    const float* __restrict__ m, const float* __restrict__ v,
    const float* __restrict__ Wc, const float* __restrict__ bc,
    float* __restrict__ out) {
    int t = threadIdx.x & 63;  // lane = channel
    int i = blockIdx.x * 2 + (threadIdx.x >> 6);
    if (i >= NN) return;
    float xr_t = xlr[(size_t)i * 128 + 64 + t];
    float att_t = att[t];
    int row = rowstart[i], end = rowstart[i + 1];
    float s = 0.f, acc = 0.f;
    int j = row;
    for (; j + 4 <= end; j += 4) {
        int s0 = ssrc[j], s1 = ssrc[j + 1], s2 = ssrc[j + 2], s3 = ssrc[j + 3];
        float v0 = xlr[(size_t)s0 * 128 + t];
        float v1 = xlr[(size_t)s1 * 128 + t];
        float v2 = xlr[(size_t)s2 * 128 + t];
        float v3 = xlr[(size_t)s3 * 128 + t];
        float w0 = att_t * LRELU(v0 + xr_t);
        float w1 = att_t * LRELU(v1 + xr_t);
        float w2 = att_t * LRELU(v2 + xr_t);
        float w3 = att_t * LRELU(v3 + xr_t);
#pragma unroll
        for (int o = 32; o >= 1; o >>= 1) {
            w0 += __shfl_xor(w0, o, 64);
            w1 += __shfl_xor(w1, o, 64);
            w2 += __shfl_xor(w2, o, 64);
            w3 += __shfl_xor(w3, o, 64);
        }
        float p0 = __expf(w0), p1 = __expf(w1), p2 = __expf(w2), p3 = __expf(w3);
        s += (p0 + p1) + (p2 + p3);
        acc += p0 * v0 + p1 * v1 + p2 * v2 + p3 * v3;
    }
    for (; j < end; j++) {
        int src = ssrc[j];
        float vv = xlr[(size_t)src * 128 + t];
        float w = att_t * LRELU(vv + xr_t);
#pragma unroll
        for (int o = 32; o >= 1; o >>= 1) w += __shfl_xor(w, o, 64);
        float p = __expf(w);
        s += p;
        acc += p * vv;
    }
    float o = acc / s + bias[t];
    o = (o - m[t]) * rsqrtf(v[t] + 1e-5f) * g[t] + b[t];
    o = (o > 0.f) ? o : (__expf(o) - 1.f);  // ELU
    // classifier: sigmoid(h2 . Wc + bc)
    float z = o * Wc[t];
#pragma unroll
    for (int off = 32; off >= 1; off >>= 1) z += __shfl_xor(z, off, 64);
    if (t == 0) out[i] = 1.f / (1.f + __expf(-(z + bc[0])));
}

// ---------------- launch ----------------

extern "C" void kernel_launch(void* const* d_in, const int* in_sizes, int n_in,
                              void* d_out, int out_size, void* d_ws, size_t ws_size,
                              hipStream_t stream) {
    const float* x    = (const float*)d_in[0];
    const int*   ei   = (const int*)d_in[1];
    const float* W1l  = (const float*)d_in[2];
    const float* b1l  = (const float*)d_in[3];
    const float* W1r  = (const float*)d_in[4];
    const float* b1r  = (const float*)d_in[5];
    const float* att1 = (const float*)d_in[6];
    const float* bias1= (const float*)d_in[7];
    const float* bn1g = (const float*)d_in[8];
    const float* bn1b = (const float*)d_in[9];
    const float* bn1m = (const float*)d_in[10];
    const float* bn1v = (const float*)d_in[11];
    const float* W2l  = (const float*)d_in[12];
    const float* b2l  = (const float*)d_in[13];
    const float* W2r  = (const float*)d_in[14];
    const float* b2r  = (const float*)d_in[15];
    const float* att2 = (const float*)d_in[16];
    const float* bias2= (const float*)d_in[17];
    const float* bn2g = (const float*)d_in[18];
    const float* bn2b = (const float*)d_in[19];
    const float* bn2m = (const float*)d_in[20];
    const float* bn2v = (const float*)d_in[21];
    const float* Wc   = (const float*)d_in[22];
    const float* bc   = (const float*)d_in[23];
    float* out = (float*)d_out;

    // workspace layout (256B-aligned slots)
    char* ws = (char*)d_ws;
    size_t off = 0;
    auto alloc = [&](size_t bytes) {
        size_t o = off;
        off += (bytes + 255) & ~(size_t)255;
        return o;
    };
    float* xlr1 = (float*)(ws + alloc((size_t)NN * 256 * 4));  // [xl1|xr1]; reused as xlr2
    float* h1   = (float*)(ws + alloc((size_t)NN * C1 * 4));
    int* deg      = (int*)(ws + alloc((size_t)NN * 4));
    int* incl     = (int*)(ws + alloc((size_t)NN * 4));
    int* rowstart = (int*)(ws + alloc((size_t)(NN + 1) * 4));
    int* writeptr = (int*)(ws + alloc((size_t)NN * 4));
    int* totals   = (int*)(ws + alloc(64 * 4));
    int* chunkoff = (int*)(ws + alloc(64 * 4));
    int* ssrc     = (int*)(ws + alloc((size_t)TE * 4));
    float* xlr2 = xlr1;

    // CSR build
    k_zero<<<(NN + 255) / 256, 256, 0, stream>>>(deg, NN);
    k_count<<<(TE + 255) / 256, 256, 0, stream>>>(ei, deg);
    k_scan1<<<NCHUNK, 1024, 0, stream>>>(deg, incl, totals);
    k_scan2<<<1, 64, 0, stream>>>(totals, chunkoff);
    k_scan3<<<(NN + 255) / 256, 256, 0, stream>>>(incl, deg, chunkoff, rowstart, writeptr);
    k_scatter<<<(TE + 255) / 256, 256, 0, stream>>>(ei, writeptr, ssrc);

    // layer 1: one fused GEMM writes [xl1 | xr1] (N = 256)
    dim3 g1((NN + 63) / 64, 256 / 64);
    k_gemm2<INC, C1><<<g1, 256, 0, stream>>>(x, W1l, W1r, b1l, b1r, xlr1, NN);
    k_node1<<<NN, 128, 0, stream>>>(xlr1, rowstart, ssrc, att1, bias1,
                                    bn1g, bn1b, bn1m, bn1v, h1);

    // layer 2 (+classifier fused): fused GEMM writes [xl2 | xr2] (N = 128)
    dim3 g2((NN + 63) / 64, 128 / 64);
    k_gemm2<C1, C2><<<g2, 256, 0, stream>>>(h1, W2l, W2r, b2l, b2r, xlr2, NN);
    k_node2<<<(NN + 1) / 2, 128, 0, stream>>>(xlr2, rowstart, ssrc, att2, bias2,
                                              bn2g, bn2b, bn2m, bn2v, Wc, bc, out);
}

// Round 3
// 447.905 us; speedup vs baseline: 1.4279x; 1.2461x over previous
//
#include <hip/hip_runtime.h>
#include <hip/hip_bf16.h>
#include <cstddef>

#define NN 50000
#define EE 800000
#define TE 850000   // EE + NN self loops
#define INC 256
#define C1 128      // heads(2) * hid(64)
#define C2 64
#define NCHUNK 49   // ceil(NN/1024)

typedef unsigned short ushort_t;
typedef short bf16x8 __attribute__((ext_vector_type(8)));
typedef float f32x4 __attribute__((ext_vector_type(4)));

__device__ inline ushort_t bf16r(float f) {  // RNE float->bf16
    unsigned u = __float_as_uint(f);
    unsigned r = (u + 0x7fffu + ((u >> 16) & 1u)) >> 16;
    return (ushort_t)r;
}
#define BF2F(u) (__uint_as_float(((unsigned)(u)) << 16))
#define LRELU(e) ((e) > 0.f ? (e) : 0.2f * (e))

// ---------------- CSR build ----------------

__global__ void k_zero(int* p, int n) {
    int i = blockIdx.x * blockDim.x + threadIdx.x;
    if (i < n) p[i] = 0;
}

__global__ void k_count(const int* __restrict__ ei, int* __restrict__ deg) {
    int e = blockIdx.x * blockDim.x + threadIdx.x;
    if (e >= TE) return;
    int dst = (e < EE) ? ei[EE + e] : (e - EE);
    atomicAdd(&deg[dst], 1);
}

__global__ void k_scan1(const int* __restrict__ deg, int* __restrict__ incl,
                        int* __restrict__ totals) {
    __shared__ int lds[1024];
    int t = threadIdx.x;
    int i = blockIdx.x * 1024 + t;
    int v = (i < NN) ? deg[i] : 0;
    lds[t] = v;
    __syncthreads();
    for (int off = 1; off < 1024; off <<= 1) {
        int add = (t >= off) ? lds[t - off] : 0;
        __syncthreads();
        lds[t] += add;
        __syncthreads();
    }
    if (i < NN) incl[i] = lds[t];
    if (t == 1023) totals[blockIdx.x] = lds[t];
}

__global__ void k_scan2(const int* __restrict__ totals, int* __restrict__ chunkoff) {
    int t = threadIdx.x;
    int orig = (t < NCHUNK) ? totals[t] : 0;
    int v = orig;
    for (int off = 1; off < 64; off <<= 1) {
        int u = __shfl_up(v, off, 64);
        if (t >= off) v += u;
    }
    if (t < NCHUNK) chunkoff[t] = v - orig;
}

__global__ void k_scan3(const int* __restrict__ incl, const int* __restrict__ deg,
                        const int* __restrict__ chunkoff, int* __restrict__ rowstart,
                        int* __restrict__ writeptr) {
    int i = blockIdx.x * blockDim.x + threadIdx.x;
    if (i == 0) rowstart[NN] = TE;
    if (i >= NN) return;
    int rs = incl[i] - deg[i] + chunkoff[i >> 10];
    rowstart[i] = rs;
    writeptr[i] = rs;
}

__global__ void k_scatter(const int* __restrict__ ei, int* __restrict__ writeptr,
                          int* __restrict__ ssrc) {
    int e = blockIdx.x * blockDim.x + threadIdx.x;
    if (e >= TE) return;
    int s, d;
    if (e < EE) { s = ei[e]; d = ei[EE + e]; }
    else        { s = e - EE; d = s; }
    int pos = atomicAdd(&writeptr[d], 1);
    ssrc[pos] = s;
}

// ---------------- casts / weight prep ----------------

__global__ void k_cast4(const float* __restrict__ src, ushort_t* __restrict__ dst, int n4) {
    int i = blockIdx.x * blockDim.x + threadIdx.x;
    if (i >= n4) return;
    float4 a = ((const float4*)src)[i];
    ushort4 o;
    o.x = bf16r(a.x); o.y = bf16r(a.y); o.z = bf16r(a.z); o.w = bf16r(a.w);
    ((ushort4*)dst)[i] = o;
}

// Wt[n][k] (bf16) from Wl/Wr [K][HALF]; biasf = [bl|br]. grid = 2*HALF blocks of K thr.
__global__ void k_prep_w(const float* __restrict__ Wl, const float* __restrict__ Wr,
                         const float* __restrict__ bl, const float* __restrict__ br,
                         ushort_t* __restrict__ Wt, float* __restrict__ biasf,
                         int K, int HALF) {
    int n = blockIdx.x;
    int k = threadIdx.x;
    const float* W = (n < HALF) ? Wl : Wr;
    int c = (n < HALF) ? n : n - HALF;
    Wt[(size_t)n * K + k] = bf16r(W[(size_t)k * HALF + c]);
    if (n == 0 && k < 2 * HALF) biasf[k] = (k < HALF) ? bl[k] : br[k - HALF];
}

// ---------------- bf16 MFMA GEMM ----------------
// C[M,NCOL](bf16) = A[M,K](bf16) @ Bt[NCOL,K]^T + bias(fp32)
// 128x128 tile, BK=32, 256 threads (4 waves, each 64x64), 16x16x32 MFMA.
// LDS rows padded to 40 bf16 (80 B = 20-bank stride): only free 2-way conflicts.

template <int K, int NCOL>
__global__ __launch_bounds__(256) void k_gemm_mfma(const ushort_t* __restrict__ A,
                                                   const ushort_t* __restrict__ Bt,
                                                   const float* __restrict__ bias,
                                                   ushort_t* __restrict__ C, int M) {
    __shared__ __align__(16) ushort_t As[128 * 40];
    __shared__ __align__(16) ushort_t Bs[128 * 40];
    int tid = threadIdx.x;
    int bm = blockIdx.x * 128;
    int bn = blockIdx.y * 128;
    int w = tid >> 6, l = tid & 63;
    int wm = (w & 1) * 64, wn = (w >> 1) * 64;
    int lm = l & 15, half = l >> 4;  // frag row/col & k-quad

    f32x4 zero = {0.f, 0.f, 0.f, 0.f};
    f32x4 acc[4][4];
#pragma unroll
    for (int a = 0; a < 4; a++)
#pragma unroll
        for (int b = 0; b < 4; b++) acc[a][b] = zero;

    for (int k0 = 0; k0 < K; k0 += 32) {
#pragma unroll
        for (int q = 0; q < 2; q++) {
            int seg = q * 256 + tid;       // 512 segments x 16 B = 8 KB tile
            int m = seg >> 2;              // 0..127
            int ko = (seg & 3) * 8;        // 0,8,16,24
            *(float4*)&As[m * 40 + ko] = *(const float4*)&A[(size_t)(bm + m) * K + k0 + ko];
            *(float4*)&Bs[m * 40 + ko] = *(const float4*)&Bt[(size_t)(bn + m) * K + k0 + ko];
        }
        __syncthreads();
        bf16x8 af[4], bfr[4];
#pragma unroll
        for (int mi = 0; mi < 4; mi++)
            af[mi] = *(const bf16x8*)&As[(wm + mi * 16 + lm) * 40 + half * 8];
#pragma unroll
        for (int ni = 0; ni < 4; ni++)
            bfr[ni] = *(const bf16x8*)&Bs[(wn + ni * 16 + lm) * 40 + half * 8];
#pragma unroll
        for (int mi = 0; mi < 4; mi++)
#pragma unroll
            for (int ni = 0; ni < 4; ni++)
                acc[mi][ni] = __builtin_amdgcn_mfma_f32_16x16x32_bf16(
                    af[mi], bfr[ni], acc[mi][ni], 0, 0, 0);
        __syncthreads();
    }
    // C/D layout: col = lane&15, row = (lane>>4)*4 + reg
#pragma unroll
    for (int ni = 0; ni < 4; ni++) {
        int col = bn + wn + ni * 16 + lm;
        float bv = bias[col];
#pragma unroll
        for (int mi = 0; mi < 4; mi++) {
            int rbase = bm + wm + mi * 16 + half * 4;
#pragma unroll
            for (int r = 0; r < 4; r++) {
                int row = rbase + r;
                if (row < M) C[(size_t)row * NCOL + col] = bf16r(acc[mi][ni][r] + bv);
            }
        }
    }
}

// ---------------- fused per-node GATv2 aggregation (bf16 in) ----------------

// Layer 1: block=128 (2 waves), wave = head, lane = channel; xlr row = [xl(128)|xr(128)] bf16.
__global__ __launch_bounds__(128) void k_node1(
    const ushort_t* __restrict__ xlr,
    const int* __restrict__ rowstart, const int* __restrict__ ssrc,
    const float* __restrict__ att, const float* __restrict__ bias,
    const float* __restrict__ g, const float* __restrict__ b,
    const float* __restrict__ m, const float* __restrict__ v,
    ushort_t* __restrict__ out) {
    int i = blockIdx.x;
    int t = threadIdx.x;
    float xr_t = BF2F(xlr[(size_t)i * 256 + 128 + t]);
    float att_t = att[t];
    int row = rowstart[i], end = rowstart[i + 1];
    float s = 0.f, acc = 0.f;
    int j = row;
    for (; j + 4 <= end; j += 4) {
        int s0 = ssrc[j], s1 = ssrc[j + 1], s2 = ssrc[j + 2], s3 = ssrc[j + 3];
        float v0 = BF2F(xlr[(size_t)s0 * 256 + t]);
        float v1 = BF2F(xlr[(size_t)s1 * 256 + t]);
        float v2 = BF2F(xlr[(size_t)s2 * 256 + t]);
        float v3 = BF2F(xlr[(size_t)s3 * 256 + t]);
        float w0 = att_t * LRELU(v0 + xr_t);
        float w1 = att_t * LRELU(v1 + xr_t);
        float w2 = att_t * LRELU(v2 + xr_t);
        float w3 = att_t * LRELU(v3 + xr_t);
#pragma unroll
        for (int o = 32; o >= 1; o >>= 1) {
            w0 += __shfl_xor(w0, o, 64);
            w1 += __shfl_xor(w1, o, 64);
            w2 += __shfl_xor(w2, o, 64);
            w3 += __shfl_xor(w3, o, 64);
        }
        float p0 = __expf(w0), p1 = __expf(w1), p2 = __expf(w2), p3 = __expf(w3);
        s += (p0 + p1) + (p2 + p3);
        acc += p0 * v0 + p1 * v1 + p2 * v2 + p3 * v3;
    }
    for (; j < end; j++) {
        int src = ssrc[j];
        float vv = BF2F(xlr[(size_t)src * 256 + t]);
        float w = att_t * LRELU(vv + xr_t);
#pragma unroll
        for (int o = 32; o >= 1; o >>= 1) w += __shfl_xor(w, o, 64);
        float p = __expf(w);
        s += p;
        acc += p * vv;
    }
    float o = acc / s + bias[t];
    o = (o - m[t]) * rsqrtf(v[t] + 1e-5f) * g[t] + b[t];
    o = (o > 0.f) ? o : (__expf(o) - 1.f);  // ELU
    out[(size_t)i * C1 + t] = bf16r(o);
}

// Layer 2 (H=1,C=64) + classifier fused: 2 nodes/block; xlr row = [xl(64)|xr(64)] bf16.
__global__ __launch_bounds__(128) void k_node2(
    const ushort_t* __restrict__ xlr,
    const int* __restrict__ rowstart, const int* __restrict__ ssrc,
    const float* __restrict__ att, const float* __restrict__ bias,
    const float* __restrict__ g, const float* __restrict__ b,
    const float* __restrict__ m, const float* __restrict__ v,
    const float* __restrict__ Wc, const float* __restrict__ bc,
    float* __restrict__ out) {
    int t = threadIdx.x & 63;
    int i = blockIdx.x * 2 + (threadIdx.x >> 6);
    if (i >= NN) return;
    float xr_t = BF2F(xlr[(size_t)i * 128 + 64 + t]);
    float att_t = att[t];
    int row = rowstart[i], end = rowstart[i + 1];
    float s = 0.f, acc = 0.f;
    int j = row;
    for (; j + 4 <= end; j += 4) {
        int s0 = ssrc[j], s1 = ssrc[j + 1], s2 = ssrc[j + 2], s3 = ssrc[j + 3];
        float v0 = BF2F(xlr[(size_t)s0 * 128 + t]);
        float v1 = BF2F(xlr[(size_t)s1 * 128 + t]);
        float v2 = BF2F(xlr[(size_t)s2 * 128 + t]);
        float v3 = BF2F(xlr[(size_t)s3 * 128 + t]);
        float w0 = att_t * LRELU(v0 + xr_t);
        float w1 = att_t * LRELU(v1 + xr_t);
        float w2 = att_t * LRELU(v2 + xr_t);
        float w3 = att_t * LRELU(v3 + xr_t);
#pragma unroll
        for (int o = 32; o >= 1; o >>= 1) {
            w0 += __shfl_xor(w0, o, 64);
            w1 += __shfl_xor(w1, o, 64);
            w2 += __shfl_xor(w2, o, 64);
            w3 += __shfl_xor(w3, o, 64);
        }
        float p0 = __expf(w0), p1 = __expf(w1), p2 = __expf(w2), p3 = __expf(w3);
        s += (p0 + p1) + (p2 + p3);
        acc += p0 * v0 + p1 * v1 + p2 * v2 + p3 * v3;
    }
    for (; j < end; j++) {
        int src = ssrc[j];
        float vv = BF2F(xlr[(size_t)src * 128 + t]);
        float w = att_t * LRELU(vv + xr_t);
#pragma unroll
        for (int o = 32; o >= 1; o >>= 1) w += __shfl_xor(w, o, 64);
        float p = __expf(w);
        s += p;
        acc += p * vv;
    }
    float o = acc / s + bias[t];
    o = (o - m[t]) * rsqrtf(v[t] + 1e-5f) * g[t] + b[t];
    o = (o > 0.f) ? o : (__expf(o) - 1.f);  // ELU
    float z = o * Wc[t];
#pragma unroll
    for (int off = 32; off >= 1; off >>= 1) z += __shfl_xor(z, off, 64);
    if (t == 0) out[i] = 1.f / (1.f + __expf(-(z + bc[0])));
}

// ---------------- launch ----------------

extern "C" void kernel_launch(void* const* d_in, const int* in_sizes, int n_in,
                              void* d_out, int out_size, void* d_ws, size_t ws_size,
                              hipStream_t stream) {
    const float* x    = (const float*)d_in[0];
    const int*   ei   = (const int*)d_in[1];
    const float* W1l  = (const float*)d_in[2];
    const float* b1l  = (const float*)d_in[3];
    const float* W1r  = (const float*)d_in[4];
    const float* b1r  = (const float*)d_in[5];
    const float* att1 = (const float*)d_in[6];
    const float* bias1= (const float*)d_in[7];
    const float* bn1g = (const float*)d_in[8];
    const float* bn1b = (const float*)d_in[9];
    const float* bn1m = (const float*)d_in[10];
    const float* bn1v = (const float*)d_in[11];
    const float* W2l  = (const float*)d_in[12];
    const float* b2l  = (const float*)d_in[13];
    const float* W2r  = (const float*)d_in[14];
    const float* b2r  = (const float*)d_in[15];
    const float* att2 = (const float*)d_in[16];
    const float* bias2= (const float*)d_in[17];
    const float* bn2g = (const float*)d_in[18];
    const float* bn2b = (const float*)d_in[19];
    const float* bn2m = (const float*)d_in[20];
    const float* bn2v = (const float*)d_in[21];
    const float* Wc   = (const float*)d_in[22];
    const float* bc   = (const float*)d_in[23];
    float* out = (float*)d_out;

    char* ws = (char*)d_ws;
    size_t off = 0;
    auto alloc = [&](size_t bytes) {
        size_t o = off;
        off += (bytes + 255) & ~(size_t)255;
        return o;
    };
    // padded to +128 rows where used as GEMM A-input (OOB tile reads stay in ws)
    ushort_t* xb    = (ushort_t*)(ws + alloc((size_t)(NN + 128) * 256 * 2));
    ushort_t* xlr1  = (ushort_t*)(ws + alloc((size_t)NN * 256 * 2));  // reused as xlr2
    ushort_t* h1b   = (ushort_t*)(ws + alloc((size_t)(NN + 128) * 128 * 2));
    ushort_t* Wt1   = (ushort_t*)(ws + alloc((size_t)256 * 256 * 2));
    float*    biasf1= (float*)(ws + alloc(256 * 4));
    ushort_t* Wt2   = (ushort_t*)(ws + alloc((size_t)128 * 128 * 2));
    float*    biasf2= (float*)(ws + alloc(128 * 4));
    int* deg      = (int*)(ws + alloc((size_t)NN * 4));
    int* incl     = (int*)(ws + alloc((size_t)NN * 4));
    int* rowstart = (int*)(ws + alloc((size_t)(NN + 1) * 4));
    int* writeptr = (int*)(ws + alloc((size_t)NN * 4));
    int* totals   = (int*)(ws + alloc(64 * 4));
    int* chunkoff = (int*)(ws + alloc(64 * 4));
    int* ssrc     = (int*)(ws + alloc((size_t)TE * 4));
    ushort_t* xlr2 = xlr1;

    // CSR build
    k_zero<<<(NN + 255) / 256, 256, 0, stream>>>(deg, NN);
    k_count<<<(TE + 255) / 256, 256, 0, stream>>>(ei, deg);
    k_scan1<<<NCHUNK, 1024, 0, stream>>>(deg, incl, totals);
    k_scan2<<<1, 64, 0, stream>>>(totals, chunkoff);
    k_scan3<<<(NN + 255) / 256, 256, 0, stream>>>(incl, deg, chunkoff, rowstart, writeptr);
    k_scatter<<<(TE + 255) / 256, 256, 0, stream>>>(ei, writeptr, ssrc);

    // bf16 prep
    int n4x = NN * INC / 4;
    k_cast4<<<(n4x + 255) / 256, 256, 0, stream>>>(x, xb, n4x);
    k_prep_w<<<256, 256, 0, stream>>>(W1l, W1r, b1l, b1r, Wt1, biasf1, 256, 128);
    k_prep_w<<<128, 128, 0, stream>>>(W2l, W2r, b2l, b2r, Wt2, biasf2, 128, 64);

    // layer 1
    dim3 gg1((NN + 127) / 128, 2);
    k_gemm_mfma<256, 256><<<gg1, 256, 0, stream>>>(xb, Wt1, biasf1, xlr1, NN);
    k_node1<<<NN, 128, 0, stream>>>(xlr1, rowstart, ssrc, att1, bias1,
                                    bn1g, bn1b, bn1m, bn1v, h1b);

    // layer 2 (+classifier)
    dim3 gg2((NN + 127) / 128, 1);
    k_gemm_mfma<128, 128><<<gg2, 256, 0, stream>>>(h1b, Wt2, biasf2, xlr2, NN);
    k_node2<<<(NN + 1) / 2, 128, 0, stream>>>(xlr2, rowstart, ssrc, att2, bias2,
                                              bn2g, bn2b, bn2m, bn2v, Wc, bc, out);
}

// Round 4
// 403.923 us; speedup vs baseline: 1.5834x; 1.1089x over previous
//
#include <hip/hip_runtime.h>
#include <hip/hip_bf16.h>
#include <cstddef>

#define NN 50000
#define EE 800000
#define TE 850000   // EE + NN self loops
#define INC 256
#define C1 128      // heads(2) * hid(64)
#define C2 64
#define NCHUNK 49   // ceil(NN/1024)

typedef unsigned short ushort_t;
typedef short bf16x8 __attribute__((ext_vector_type(8)));
typedef float f32x4 __attribute__((ext_vector_type(4)));

__device__ inline ushort_t bf16r(float f) {  // RNE float->bf16
    unsigned u = __float_as_uint(f);
    unsigned r = (u + 0x7fffu + ((u >> 16) & 1u)) >> 16;
    return (ushort_t)r;
}
#define BF2F(u) (__uint_as_float(((unsigned)(u)) << 16))

// ---------------- CSR build ----------------

__global__ void k_zero(int* p, int n) {
    int i = blockIdx.x * blockDim.x + threadIdx.x;
    if (i < n) p[i] = 0;
}

__global__ void k_count(const int* __restrict__ ei, int* __restrict__ deg) {
    int e = blockIdx.x * blockDim.x + threadIdx.x;
    if (e >= TE) return;
    int dst = (e < EE) ? ei[EE + e] : (e - EE);
    atomicAdd(&deg[dst], 1);
}

__global__ void k_scan1(const int* __restrict__ deg, int* __restrict__ incl,
                        int* __restrict__ totals) {
    __shared__ int lds[1024];
    int t = threadIdx.x;
    int i = blockIdx.x * 1024 + t;
    int v = (i < NN) ? deg[i] : 0;
    lds[t] = v;
    __syncthreads();
    for (int off = 1; off < 1024; off <<= 1) {
        int add = (t >= off) ? lds[t - off] : 0;
        __syncthreads();
        lds[t] += add;
        __syncthreads();
    }
    if (i < NN) incl[i] = lds[t];
    if (t == 1023) totals[blockIdx.x] = lds[t];
}

__global__ void k_scan2(const int* __restrict__ totals, int* __restrict__ chunkoff) {
    int t = threadIdx.x;
    int orig = (t < NCHUNK) ? totals[t] : 0;
    int v = orig;
    for (int off = 1; off < 64; off <<= 1) {
        int u = __shfl_up(v, off, 64);
        if (t >= off) v += u;
    }
    if (t < NCHUNK) chunkoff[t] = v - orig;
}

__global__ void k_scan3(const int* __restrict__ incl, const int* __restrict__ deg,
                        const int* __restrict__ chunkoff, int* __restrict__ rowstart,
                        int* __restrict__ writeptr) {
    int i = blockIdx.x * blockDim.x + threadIdx.x;
    if (i == 0) rowstart[NN] = TE;
    if (i >= NN) return;
    int rs = incl[i] - deg[i] + chunkoff[i >> 10];
    rowstart[i] = rs;
    writeptr[i] = rs;
}

__global__ void k_scatter(const int* __restrict__ ei, int* __restrict__ writeptr,
                          int* __restrict__ ssrc, int* __restrict__ sdst) {
    int e = blockIdx.x * blockDim.x + threadIdx.x;
    if (e >= TE) return;
    int s, d;
    if (e < EE) { s = ei[e]; d = ei[EE + e]; }
    else        { s = e - EE; d = s; }
    int pos = atomicAdd(&writeptr[d], 1);
    ssrc[pos] = s;
    sdst[pos] = d;
}

// ---------------- casts / weight prep ----------------

__global__ void k_cast4(const float* __restrict__ src, ushort_t* __restrict__ dst, int n4) {
    int i = blockIdx.x * blockDim.x + threadIdx.x;
    if (i >= n4) return;
    float4 a = ((const float4*)src)[i];
    ushort4 o;
    o.x = bf16r(a.x); o.y = bf16r(a.y); o.z = bf16r(a.z); o.w = bf16r(a.w);
    ((ushort4*)dst)[i] = o;
}

__global__ void k_prep_w(const float* __restrict__ Wl, const float* __restrict__ Wr,
                         const float* __restrict__ bl, const float* __restrict__ br,
                         ushort_t* __restrict__ Wt, float* __restrict__ biasf,
                         int K, int HALF) {
    int n = blockIdx.x;
    int k = threadIdx.x;
    const float* W = (n < HALF) ? Wl : Wr;
    int c = (n < HALF) ? n : n - HALF;
    Wt[(size_t)n * K + k] = bf16r(W[(size_t)k * HALF + c]);
    if (n == 0 && k < 2 * HALF) biasf[k] = (k < HALF) ? bl[k] : br[k - HALF];
}

// ---------------- bf16 MFMA GEMM ----------------
// C[M,NCOL](bf16) = A[M,K](bf16) @ Bt[NCOL,K]^T + bias(fp32)
// 128x128 tile, BK=32, 256 threads, 16x16x32 MFMA; LDS rows padded to 40 bf16.

template <int K, int NCOL>
__global__ __launch_bounds__(256) void k_gemm_mfma(const ushort_t* __restrict__ A,
                                                   const ushort_t* __restrict__ Bt,
                                                   const float* __restrict__ bias,
                                                   ushort_t* __restrict__ C, int M) {
    __shared__ __align__(16) ushort_t As[128 * 40];
    __shared__ __align__(16) ushort_t Bs[128 * 40];
    int tid = threadIdx.x;
    int bm = blockIdx.x * 128;
    int bn = blockIdx.y * 128;
    int w = tid >> 6, l = tid & 63;
    int wm = (w & 1) * 64, wn = (w >> 1) * 64;
    int lm = l & 15, half = l >> 4;

    f32x4 zero = {0.f, 0.f, 0.f, 0.f};
    f32x4 acc[4][4];
#pragma unroll
    for (int a = 0; a < 4; a++)
#pragma unroll
        for (int b = 0; b < 4; b++) acc[a][b] = zero;

    for (int k0 = 0; k0 < K; k0 += 32) {
#pragma unroll
        for (int q = 0; q < 2; q++) {
            int seg = q * 256 + tid;
            int m = seg >> 2;
            int ko = (seg & 3) * 8;
            *(float4*)&As[m * 40 + ko] = *(const float4*)&A[(size_t)(bm + m) * K + k0 + ko];
            *(float4*)&Bs[m * 40 + ko] = *(const float4*)&Bt[(size_t)(bn + m) * K + k0 + ko];
        }
        __syncthreads();
        bf16x8 af[4], bfr[4];
#pragma unroll
        for (int mi = 0; mi < 4; mi++)
            af[mi] = *(const bf16x8*)&As[(wm + mi * 16 + lm) * 40 + half * 8];
#pragma unroll
        for (int ni = 0; ni < 4; ni++)
            bfr[ni] = *(const bf16x8*)&Bs[(wn + ni * 16 + lm) * 40 + half * 8];
#pragma unroll
        for (int mi = 0; mi < 4; mi++)
#pragma unroll
            for (int ni = 0; ni < 4; ni++)
                acc[mi][ni] = __builtin_amdgcn_mfma_f32_16x16x32_bf16(
                    af[mi], bfr[ni], acc[mi][ni], 0, 0, 0);
        __syncthreads();
    }
#pragma unroll
    for (int ni = 0; ni < 4; ni++) {
        int col = bn + wn + ni * 16 + lm;
        float bv = bias[col];
#pragma unroll
        for (int mi = 0; mi < 4; mi++) {
            int rbase = bm + wm + mi * 16 + half * 4;
#pragma unroll
            for (int r = 0; r < 4; r++) {
                int row = rbase + r;
                if (row < M) C[(size_t)row * NCOL + col] = bf16r(acc[mi][ni][r] + bv);
            }
        }
    }
}

// ---------------- Pass A: edge-parallel logits ----------------
// 4 lanes per edge; lane q of a quad covers chunk c = q + 4*it (8 channels each).
// STRIDE = row stride in elements (xl at [0,STRIDE/2), xr at [STRIDE/2,STRIDE)).
// ITS = (STRIDE/2)/8/4 chunks per lane. HEADS: 2 -> it<ITS/2 is head0.

__device__ inline float lrelu_dot2(unsigned ua, unsigned ub, float at_lo, float at_hi) {
    float alo = __uint_as_float(ua << 16), ahi = __uint_as_float(ua & 0xffff0000u);
    float blo = __uint_as_float(ub << 16), bhi = __uint_as_float(ub & 0xffff0000u);
    float t0 = alo + blo, t1 = ahi + bhi;
    float l0 = fmaxf(t0, 0.f) + 0.2f * fminf(t0, 0.f);
    float l1 = fmaxf(t1, 0.f) + 0.2f * fminf(t1, 0.f);
    return at_lo * l0 + at_hi * l1;
}

template <int STRIDE, int ITS, int HEADS>
__global__ __launch_bounds__(256) void k_edge(
    const ushort_t* __restrict__ xlr,
    const int* __restrict__ ssrc, const int* __restrict__ sdst,
    const float* __restrict__ att, float* __restrict__ p) {
    int l = threadIdx.x & 63;
    int wv = threadIdx.x >> 6;
    int q = l & 3;
    int j = blockIdx.x * 64 + wv * 16 + (l >> 2);
    if (j >= TE) return;
    int src = ssrc[j], dst = sdst[j];
    const ushort_t* xl = xlr + (size_t)src * STRIDE;
    const ushort_t* xr = xlr + (size_t)dst * STRIDE + STRIDE / 2;
    float w[HEADS];
#pragma unroll
    for (int h = 0; h < HEADS; h++) w[h] = 0.f;
#pragma unroll
    for (int it = 0; it < ITS; it++) {
        int c = q + 4 * it;  // chunk of 8 channels
        uint4 a = *(const uint4*)&xl[c * 8];
        uint4 b = *(const uint4*)&xr[c * 8];
        float4 t0 = *(const float4*)&att[c * 8];
        float4 t1 = *(const float4*)&att[c * 8 + 4];
        int h = (HEADS == 2 && it >= ITS / 2) ? 1 : 0;
        float d = lrelu_dot2(a.x, b.x, t0.x, t0.y)
                + lrelu_dot2(a.y, b.y, t0.z, t0.w)
                + lrelu_dot2(a.z, b.z, t1.x, t1.y)
                + lrelu_dot2(a.w, b.w, t1.z, t1.w);
        w[h] += d;
    }
#pragma unroll
    for (int h = 0; h < HEADS; h++) {
        w[h] += __shfl_xor(w[h], 1, 64);
        w[h] += __shfl_xor(w[h], 2, 64);
    }
    if (q == 0) {
        if (HEADS == 2)
            ((float2*)p)[j] = make_float2(__expf(w[0]), __expf(w[1]));
        else
            p[j] = __expf(w[0]);
    }
}

// ---------------- Pass B: node-parallel aggregation + epilogue ----------------

// Layer 1: block=128 (2 waves), t = output channel (head = t>>6); p = float2/edge.
__global__ __launch_bounds__(128) void k_aggr1(
    const ushort_t* __restrict__ xlr, const float* __restrict__ p,
    const int* __restrict__ rowstart, const int* __restrict__ ssrc,
    const float* __restrict__ bias,
    const float* __restrict__ g, const float* __restrict__ b,
    const float* __restrict__ m, const float* __restrict__ v,
    ushort_t* __restrict__ out) {
    int i = blockIdx.x;
    int t = threadIdx.x;
    int h = t >> 6;
    int row = rowstart[i], end = rowstart[i + 1];
    float s = 0.f, acc = 0.f;
    int j = row;
    for (; j + 4 <= end; j += 4) {
        int s0 = ssrc[j], s1 = ssrc[j + 1], s2 = ssrc[j + 2], s3 = ssrc[j + 3];
        float p0 = p[2 * j + h], p1 = p[2 * (j + 1) + h];
        float p2 = p[2 * (j + 2) + h], p3 = p[2 * (j + 3) + h];
        float v0 = BF2F(xlr[(size_t)s0 * 256 + t]);
        float v1 = BF2F(xlr[(size_t)s1 * 256 + t]);
        float v2 = BF2F(xlr[(size_t)s2 * 256 + t]);
        float v3 = BF2F(xlr[(size_t)s3 * 256 + t]);
        s += (p0 + p1) + (p2 + p3);
        acc += p0 * v0 + p1 * v1 + p2 * v2 + p3 * v3;
    }
    for (; j < end; j++) {
        float pj = p[2 * j + h];
        float vv = BF2F(xlr[(size_t)ssrc[j] * 256 + t]);
        s += pj;
        acc += pj * vv;
    }
    float o = acc / s + bias[t];
    o = (o - m[t]) * rsqrtf(v[t] + 1e-5f) * g[t] + b[t];
    o = (o > 0.f) ? o : (__expf(o) - 1.f);  // ELU
    out[(size_t)i * C1 + t] = bf16r(o);
}

// Layer 2 + classifier: 2 nodes/block; p scalar/edge.
__global__ __launch_bounds__(128) void k_aggr2(
    const ushort_t* __restrict__ xlr, const float* __restrict__ p,
    const int* __restrict__ rowstart, const int* __restrict__ ssrc,
    const float* __restrict__ bias,
    const float* __restrict__ g, const float* __restrict__ b,
    const float* __restrict__ m, const float* __restrict__ v,
    const float* __restrict__ Wc, const float* __restrict__ bc,
    float* __restrict__ out) {
    int t = threadIdx.x & 63;
    int i = blockIdx.x * 2 + (threadIdx.x >> 6);
    if (i >= NN) return;
    int row = rowstart[i], end = rowstart[i + 1];
    float s = 0.f, acc = 0.f;
    int j = row;
    for (; j + 4 <= end; j += 4) {
        int s0 = ssrc[j], s1 = ssrc[j + 1], s2 = ssrc[j + 2], s3 = ssrc[j + 3];
        float p0 = p[j], p1 = p[j + 1], p2 = p[j + 2], p3 = p[j + 3];
        float v0 = BF2F(xlr[(size_t)s0 * 128 + t]);
        float v1 = BF2F(xlr[(size_t)s1 * 128 + t]);
        float v2 = BF2F(xlr[(size_t)s2 * 128 + t]);
        float v3 = BF2F(xlr[(size_t)s3 * 128 + t]);
        s += (p0 + p1) + (p2 + p3);
        acc += p0 * v0 + p1 * v1 + p2 * v2 + p3 * v3;
    }
    for (; j < end; j++) {
        float pj = p[j];
        float vv = BF2F(xlr[(size_t)ssrc[j] * 128 + t]);
        s += pj;
        acc += pj * vv;
    }
    float o = acc / s + bias[t];
    o = (o - m[t]) * rsqrtf(v[t] + 1e-5f) * g[t] + b[t];
    o = (o > 0.f) ? o : (__expf(o) - 1.f);  // ELU
    float z = o * Wc[t];
#pragma unroll
    for (int off = 32; off >= 1; off >>= 1) z += __shfl_xor(z, off, 64);
    if (t == 0) out[i] = 1.f / (1.f + __expf(-(z + bc[0])));
}

// ---------------- launch ----------------

extern "C" void kernel_launch(void* const* d_in, const int* in_sizes, int n_in,
                              void* d_out, int out_size, void* d_ws, size_t ws_size,
                              hipStream_t stream) {
    const float* x    = (const float*)d_in[0];
    const int*   ei   = (const int*)d_in[1];
    const float* W1l  = (const float*)d_in[2];
    const float* b1l  = (const float*)d_in[3];
    const float* W1r  = (const float*)d_in[4];
    const float* b1r  = (const float*)d_in[5];
    const float* att1 = (const float*)d_in[6];
    const float* bias1= (const float*)d_in[7];
    const float* bn1g = (const float*)d_in[8];
    const float* bn1b = (const float*)d_in[9];
    const float* bn1m = (const float*)d_in[10];
    const float* bn1v = (const float*)d_in[11];
    const float* W2l  = (const float*)d_in[12];
    const float* b2l  = (const float*)d_in[13];
    const float* W2r  = (const float*)d_in[14];
    const float* b2r  = (const float*)d_in[15];
    const float* att2 = (const float*)d_in[16];
    const float* bias2= (const float*)d_in[17];
    const float* bn2g = (const float*)d_in[18];
    const float* bn2b = (const float*)d_in[19];
    const float* bn2m = (const float*)d_in[20];
    const float* bn2v = (const float*)d_in[21];
    const float* Wc   = (const float*)d_in[22];
    const float* bc   = (const float*)d_in[23];
    float* out = (float*)d_out;

    char* ws = (char*)d_ws;
    size_t off = 0;
    auto alloc = [&](size_t bytes) {
        size_t o = off;
        off += (bytes + 255) & ~(size_t)255;
        return o;
    };
    ushort_t* xb    = (ushort_t*)(ws + alloc((size_t)(NN + 128) * 256 * 2));
    ushort_t* xlr1  = (ushort_t*)(ws + alloc((size_t)NN * 256 * 2));  // reused as xlr2
    ushort_t* h1b   = (ushort_t*)(ws + alloc((size_t)(NN + 128) * 128 * 2));
    ushort_t* Wt1   = (ushort_t*)(ws + alloc((size_t)256 * 256 * 2));
    float*    biasf1= (float*)(ws + alloc(256 * 4));
    ushort_t* Wt2   = (ushort_t*)(ws + alloc((size_t)128 * 128 * 2));
    float*    biasf2= (float*)(ws + alloc(128 * 4));
    int* deg      = (int*)(ws + alloc((size_t)NN * 4));
    int* incl     = (int*)(ws + alloc((size_t)NN * 4));
    int* rowstart = (int*)(ws + alloc((size_t)(NN + 1) * 4));
    int* writeptr = (int*)(ws + alloc((size_t)NN * 4));
    int* totals   = (int*)(ws + alloc(64 * 4));
    int* chunkoff = (int*)(ws + alloc(64 * 4));
    int* ssrc     = (int*)(ws + alloc((size_t)TE * 4));
    int* sdst     = (int*)(ws + alloc((size_t)TE * 4));
    float* pp     = (float*)(ws + alloc((size_t)2 * TE * 4));  // layer1 float2; layer2 float
    ushort_t* xlr2 = xlr1;

    // CSR build
    k_zero<<<(NN + 255) / 256, 256, 0, stream>>>(deg, NN);
    k_count<<<(TE + 255) / 256, 256, 0, stream>>>(ei, deg);
    k_scan1<<<NCHUNK, 1024, 0, stream>>>(deg, incl, totals);
    k_scan2<<<1, 64, 0, stream>>>(totals, chunkoff);
    k_scan3<<<(NN + 255) / 256, 256, 0, stream>>>(incl, deg, chunkoff, rowstart, writeptr);
    k_scatter<<<(TE + 255) / 256, 256, 0, stream>>>(ei, writeptr, ssrc, sdst);

    // bf16 prep
    int n4x = NN * INC / 4;
    k_cast4<<<(n4x + 255) / 256, 256, 0, stream>>>(x, xb, n4x);
    k_prep_w<<<256, 256, 0, stream>>>(W1l, W1r, b1l, b1r, Wt1, biasf1, 256, 128);
    k_prep_w<<<128, 128, 0, stream>>>(W2l, W2r, b2l, b2r, Wt2, biasf2, 128, 64);

    int eb = (TE + 63) / 64;

    // layer 1
    dim3 gg1((NN + 127) / 128, 2);
    k_gemm_mfma<256, 256><<<gg1, 256, 0, stream>>>(xb, Wt1, biasf1, xlr1, NN);
    k_edge<256, 4, 2><<<eb, 256, 0, stream>>>(xlr1, ssrc, sdst, att1, pp);
    k_aggr1<<<NN, 128, 0, stream>>>(xlr1, pp, rowstart, ssrc, bias1,
                                    bn1g, bn1b, bn1m, bn1v, h1b);

    // layer 2 (+classifier)
    dim3 gg2((NN + 127) / 128, 1);
    k_gemm_mfma<128, 128><<<gg2, 256, 0, stream>>>(h1b, Wt2, biasf2, xlr2, NN);
    k_edge<128, 2, 1><<<eb, 256, 0, stream>>>(xlr2, ssrc, sdst, att2, pp);
    k_aggr2<<<(NN + 1) / 2, 128, 0, stream>>>(xlr2, pp, rowstart, ssrc, bias2,
                                              bn2g, bn2b, bn2m, bn2v, Wc, bc, out);
}